// Round 21
// baseline (116.966 us; speedup 1.0000x reference)
//
#include <hip/hip_runtime.h>

#define B_ 4
#define N_ 2048
#define C_ 512
#define H_ 8
#define HD_ 64
#define SCALE_ 0.125f
// SCALE * log2(e): Q is pre-scaled by this so P = exp2(q.k) directly (v_exp_f32)
#define QSCALE_ 0.18033688011112042f

typedef __attribute__((ext_vector_type(8))) __bf16 bf16x8;
typedef __attribute__((ext_vector_type(4))) float f32x4;
typedef __attribute__((ext_vector_type(4))) unsigned int u32x4;
typedef __attribute__((ext_vector_type(2))) unsigned int u32x2;
typedef __attribute__((ext_vector_type(4))) short s16x4;

#if __has_builtin(__builtin_amdgcn_mfma_f32_16x16x16bf16_1k)
#define MFMA16(acc, a, b) acc = __builtin_amdgcn_mfma_f32_16x16x16bf16_1k(a, b, acc, 0, 0, 0)
#else
#define MFMA16(acc, a, b) \
    asm("v_mfma_f32_16x16x16_bf16 %0, %1, %2, %0" : "+v"(acc) : "v"(a), "v"(b))
#endif

__device__ __forceinline__ unsigned short f2bf(float f) {
    unsigned int u = __builtin_bit_cast(unsigned int, f);
    u += 0x7fffu + ((u >> 16) & 1u);
    return (unsigned short)(u >> 16);
}

__device__ __forceinline__ void llds16(const void* g, void* l) {
    __builtin_amdgcn_global_load_lds(
        (const __attribute__((address_space(1))) unsigned int*)g,
        (__attribute__((address_space(3))) unsigned int*)l, 16, 0, 0);
}

// ---------------------------------------------------------------- convert (weights only)
__global__ __launch_bounds__(256) void cvt_w(const float* __restrict__ wq,
                                             const float* __restrict__ wp,
                                             unsigned short* __restrict__ wqb,
                                             unsigned short* __restrict__ wpb) {
    const int NQ = 3 * C_ * C_ / 4, NP = C_ * C_ / 4;
    int i = blockIdx.x * 256 + threadIdx.x;
    const float4* src;
    ushort4* dst;
    int idx;
    if (i < NQ) { src = (const float4*)wq; dst = (ushort4*)wqb; idx = i; }
    else if (i < NQ + NP) { src = (const float4*)wp; dst = (ushort4*)wpb; idx = i - NQ; }
    else return;
    float4 v = src[idx];
    ushort4 o;
    o.x = f2bf(v.x); o.y = f2bf(v.y); o.z = f2bf(v.z); o.w = f2bf(v.w);
    dst[idx] = o;
}

// ---------------------------------------------------------------- GEMM1: x(f32) @ w_qkv^T
// A staged by reg: 2x global f32x4 load -> 4x v_cvt_pk_bf16_f32 (RNE, same bits
// as the old cvt kernel) -> ds_write_b128 to the SAME linear LDS slot llds16
// used. B (bf16 weights) stays global_load_lds. Epilogue: Q/K coalesced
// (B,H,N,64) writes (Q pre-scaled QSCALE_); V via LDS transpose -> Vt (B,H,64,N).
__global__ __launch_bounds__(256) void gemm_qkv(const float* __restrict__ X,
                                                const unsigned short* __restrict__ Bw,
                                                const float* __restrict__ bias,
                                                unsigned short* __restrict__ Qb,
                                                unsigned short* __restrict__ Kb,
                                                unsigned short* __restrict__ Vt) {
    constexpr int K = 512;
    __shared__ __align__(16) unsigned char smem[32768];
    unsigned char* sA = smem;
    unsigned char* sB = smem + 16384;

    const int tid = threadIdx.x;
    const int lane = tid & 63;
    const int wave = tid >> 6;
    const int wm = wave >> 1, wn = wave & 1;
    const int m0 = blockIdx.y * 128;
    const int n0 = blockIdx.x * 128;

    f32x4 acc[4][4] = {};

    for (int k0 = 0; k0 < K; k0 += 64) {
#pragma unroll
        for (int i = 0; i < 4; i++) {
            int ci = wave * 4 + i;
            int row = ci * 8 + (lane >> 3);
            int col = k0 + (lane & 7) * 8;
            // A: f32 load + convert + LDS write (linear slot = ci*1024 + lane*16)
            const float* gx = X + (size_t)(m0 + row) * K + col;
            f32x4 xa = *(const f32x4*)gx;
            f32x4 xc = *(const f32x4*)(gx + 4);
            unsigned int w0, w1, w2, w3;
            asm("v_cvt_pk_bf16_f32 %0, %1, %2" : "=v"(w0) : "v"(xa[0]), "v"(xa[1]));
            asm("v_cvt_pk_bf16_f32 %0, %1, %2" : "=v"(w1) : "v"(xa[2]), "v"(xa[3]));
            asm("v_cvt_pk_bf16_f32 %0, %1, %2" : "=v"(w2) : "v"(xc[0]), "v"(xc[1]));
            asm("v_cvt_pk_bf16_f32 %0, %1, %2" : "=v"(w3) : "v"(xc[2]), "v"(xc[3]));
            u32x4 wv;
            wv[0] = w0; wv[1] = w1; wv[2] = w2; wv[3] = w3;
            *(u32x4*)(sA + ci * 1024 + lane * 16) = wv;
            // B: bf16 async global->LDS
            const unsigned char* gb =
                (const unsigned char*)Bw + ((size_t)(n0 + row) * K + k0) * 2 + (lane & 7) * 16;
            llds16(gb, sB + ci * 1024);
        }
        __syncthreads();
#pragma unroll
        for (int kk = 0; kk < 2; kk++) {
            bf16x8 af[4], bfr[4];
#pragma unroll
            for (int mi = 0; mi < 4; mi++)
                af[mi] = *(const bf16x8*)(sA + (wm * 64 + mi * 16 + (lane & 15)) * 128 +
                                          kk * 64 + (lane >> 4) * 16);
#pragma unroll
            for (int ni = 0; ni < 4; ni++)
                bfr[ni] = *(const bf16x8*)(sB + (wn * 64 + ni * 16 + (lane & 15)) * 128 +
                                           kk * 64 + (lane >> 4) * 16);
#pragma unroll
            for (int mi = 0; mi < 4; mi++)
#pragma unroll
                for (int ni = 0; ni < 4; ni++)
                    acc[mi][ni] = __builtin_amdgcn_mfma_f32_16x16x32_bf16(
                        af[mi], bfr[ni], acc[mi][ni], 0, 0, 0);
        }
        __syncthreads();
    }

    if (n0 >= 1024) {
        // ---- V blocks: LDS transpose then coalesced d-major write
        unsigned char* T = smem;  // [128 c][128 m] bf16, byte = cl*256 + (ml*2 ^ ((cl&7)<<4))
#pragma unroll
        for (int ni = 0; ni < 4; ni++) {
            int cl = wn * 64 + ni * 16 + (lane & 15);
            float bv = bias[n0 + cl];
#pragma unroll
            for (int mi = 0; mi < 4; mi++) {
#pragma unroll
                for (int r = 0; r < 4; r++) {
                    int ml = wm * 64 + mi * 16 + ((lane >> 4) << 2) + r;
                    *(unsigned short*)(T + cl * 256 + ((ml * 2) ^ ((cl & 7) << 4))) =
                        f2bf(acc[mi][ni][r] + bv);
                }
            }
        }
        __syncthreads();
        const int b = m0 >> 11;
#pragma unroll
        for (int it = 0; it < 8; it++) {
            int li = it * 256 + tid;
            int cl2 = li >> 4, mc = li & 15;
            int cg = n0 + cl2;
            int h = (cg >> 6) & 7, d = cg & 63;
            u32x4 vv = *(const u32x4*)(T + cl2 * 256 + ((mc * 16) ^ ((cl2 & 7) << 4)));
            int n = (m0 & (N_ - 1)) + mc * 8;
            *(u32x4*)((unsigned char*)Vt +
                      (((size_t)(b * H_ + h) * HD_ + d) * N_ + n) * 2) = vv;
        }
    } else {
        // ---- Q/K blocks: direct coalesced (B,H,N,64) writes
        const bool selq = (n0 < 512);
#pragma unroll
        for (int ni = 0; ni < 4; ni++) {
            int cg = n0 + wn * 64 + ni * 16 + (lane & 15);
            int h = (cg >> 6) & 7, d = cg & 63;
            float bv = bias[cg];
#pragma unroll
            for (int mi = 0; mi < 4; mi++) {
#pragma unroll
                for (int r = 0; r < 4; r++) {
                    int m = m0 + wm * 64 + mi * 16 + ((lane >> 4) << 2) + r;
                    int b = m >> 11, n = m & (N_ - 1);
                    float fv = acc[mi][ni][r] + bv;
                    size_t idx = ((size_t)(b * H_ + h) * N_ + n) * HD_ + d;
                    if (selq) Qb[idx] = f2bf(fv * QSCALE_);
                    else Kb[idx] = f2bf(fv);
                }
            }
        }
    }
}

// ---------------------------------------------------------------- GEMM2 (proj): AO(bf16) @ w_proj^T
__global__ __launch_bounds__(256) void gemm_proj(const unsigned short* __restrict__ A,
                                                 const unsigned short* __restrict__ Bw,
                                                 const float* __restrict__ bias,
                                                 float* __restrict__ Out) {
    constexpr int K = 512;
    __shared__ __align__(16) unsigned char smem[32768];
    unsigned char* sA = smem;
    unsigned char* sB = smem + 16384;

    const int tid = threadIdx.x;
    const int lane = tid & 63;
    const int wave = tid >> 6;
    const int wm = wave >> 1, wn = wave & 1;
    const int m0 = blockIdx.y * 128;
    const int n0 = blockIdx.x * 128;

    f32x4 acc[4][4] = {};

    for (int k0 = 0; k0 < K; k0 += 64) {
#pragma unroll
        for (int i = 0; i < 4; i++) {
            int ci = wave * 4 + i;
            int row = ci * 8 + (lane >> 3);
            int cb = (lane & 7) * 16;
            const unsigned char* ga =
                (const unsigned char*)A + ((size_t)(m0 + row) * K + k0) * 2 + cb;
            const unsigned char* gb =
                (const unsigned char*)Bw + ((size_t)(n0 + row) * K + k0) * 2 + cb;
            llds16(ga, sA + ci * 1024);
            llds16(gb, sB + ci * 1024);
        }
        __syncthreads();
#pragma unroll
        for (int kk = 0; kk < 2; kk++) {
            bf16x8 af[4], bfr[4];
#pragma unroll
            for (int mi = 0; mi < 4; mi++)
                af[mi] = *(const bf16x8*)(sA + (wm * 64 + mi * 16 + (lane & 15)) * 128 +
                                          kk * 64 + (lane >> 4) * 16);
#pragma unroll
            for (int ni = 0; ni < 4; ni++)
                bfr[ni] = *(const bf16x8*)(sB + (wn * 64 + ni * 16 + (lane & 15)) * 128 +
                                           kk * 64 + (lane >> 4) * 16);
#pragma unroll
            for (int mi = 0; mi < 4; mi++)
#pragma unroll
                for (int ni = 0; ni < 4; ni++)
                    acc[mi][ni] = __builtin_amdgcn_mfma_f32_16x16x32_bf16(
                        af[mi], bfr[ni], acc[mi][ni], 0, 0, 0);
        }
        __syncthreads();
    }

#pragma unroll
    for (int ni = 0; ni < 4; ni++) {
        int c = n0 + wn * 64 + ni * 16 + (lane & 15);
        float bv = bias[c];
#pragma unroll
        for (int mi = 0; mi < 4; mi++) {
#pragma unroll
            for (int r = 0; r < 4; r++) {
                int m = m0 + wm * 64 + mi * 16 + ((lane >> 4) << 2) + r;
                Out[(size_t)m * C_ + c] = acc[mi][ni][r] + bv;
            }
        }
    }
}

// ---------------------------------------------------------------- flash attention
// R18 structure (attn 65.5us, absmax 1.95e-3): 8 waves x 16 q-rows; KVBLK=64;
// swapped QK^T -> in-register P (K=16 PV); no-max exp2 softmax; ones-MFMA row
// sums; T5 setprio around MFMA clusters; unroll-2 tile loop; XCD block swizzle.
__global__ __launch_bounds__(512, 4) void attn_fwd(const unsigned short* __restrict__ Qb,
                                                   const unsigned short* __restrict__ Kb,
                                                   const unsigned short* __restrict__ Vt,
                                                   unsigned short* __restrict__ AO) {
    __shared__ __align__(16) unsigned char smem[32768];
    // sK buf0/1: 0, 8192 | sV buf0/1: 16384, 24576

    const int tid = threadIdx.x, lane = tid & 63, wave = tid >> 6;
    const int g = lane >> 4, c = lane & 15;
    // XCD-aware bijective swizzle: each XCD (L%8) owns 4 complete bh's.
    const int L = blockIdx.y * 16 + blockIdx.x;
    const int bh = (L & 7) * 4 + ((L >> 3) & 3);
    const int qx = L >> 5;
    const int q0 = qx * 128 + wave * 16;
    const unsigned short* Qh = Qb + (size_t)bh * N_ * HD_;
    const unsigned short* Kh = Kb + (size_t)bh * N_ * HD_;
    const unsigned short* Vh = Vt + (size_t)bh * HD_ * N_;

    // Q fragments (rows q0 + c), held for the whole kernel (B-operand of swapped QK)
    bf16x8 qf[2];
#pragma unroll
    for (int kk = 0; kk < 2; kk++)
        qf[kk] = *(const bf16x8*)(Qh + (size_t)(q0 + c) * HD_ + kk * 32 + g * 8);

    s16x4 ones16;
#pragma unroll
    for (int i = 0; i < 4; i++) ones16[i] = (short)0x3F80;  // bf16 1.0

    f32x4 o[4] = {};
    f32x4 osum = {};

    // staging geometry: one 16B chunk of K and of V per thread per tile
    const int srow = tid >> 3;
    const int sslot = (tid & 7) * 16;
    const int ssw = (sslot ^ ((srow & 7) << 4));

    // prologue: stage tile 0 into buf 0
    {
        u32x4 kreg = *(const u32x4*)((const unsigned char*)Kh + (size_t)srow * 128 + sslot);
        u32x4 vreg = *(const u32x4*)((const unsigned char*)Vh + (size_t)srow * (N_ * 2) + sslot);
        *(u32x4*)(smem + srow * 128 + ssw) = kreg;
        *(u32x4*)(smem + 16384 + srow * 128 + ssw) = vreg;
    }
    __syncthreads();

#pragma unroll 2
    for (int t = 0; t < N_ / 64; t++) {
        unsigned char* bK = smem + (t & 1) * 8192;
        unsigned char* bV = smem + 16384 + (t & 1) * 8192;

        // ---- issue next tile's global loads (latency hides under compute)
        u32x4 kreg, vreg;
        if (t < N_ / 64 - 1) {
            int kv0 = (t + 1) * 64;
            kreg = *(const u32x4*)((const unsigned char*)Kh + (size_t)(kv0 + srow) * 128 + sslot);
            vreg = *(const u32x4*)((const unsigned char*)Vh + (size_t)srow * (N_ * 2) +
                                   kv0 * 2 + sslot);
        }

        // ---- S^T = K Q^T (swapped operands): lane holds S[q=c][kv=j*16+4g+r]
        f32x4 s[4] = {};
        __builtin_amdgcn_s_setprio(1);
#pragma unroll
        for (int j = 0; j < 4; j++) {
#pragma unroll
            for (int kk = 0; kk < 2; kk++) {
                int krow = j * 16 + c;
                bf16x8 kf = *(const bf16x8*)(bK + krow * 128 +
                                             ((kk * 64 + g * 16) ^ ((krow & 7) << 4)));
                s[j] = __builtin_amdgcn_mfma_f32_16x16x32_bf16(kf, qf[kk], s[j], 0, 0, 0);
            }
        }
        __builtin_amdgcn_s_setprio(0);

        // ---- P = exp2(S^T); pack in-register into K=16 A-fragments (no LDS)
        s16x4 pa[4];
#pragma unroll
        for (int j = 0; j < 4; j++) {
            float p0 = __builtin_exp2f(s[j][0]);
            float p1 = __builtin_exp2f(s[j][1]);
            float p2 = __builtin_exp2f(s[j][2]);
            float p3 = __builtin_exp2f(s[j][3]);
            unsigned int lo, hi;
            asm("v_cvt_pk_bf16_f32 %0, %1, %2" : "=v"(lo) : "v"(p0), "v"(p1));
            asm("v_cvt_pk_bf16_f32 %0, %1, %2" : "=v"(hi) : "v"(p2), "v"(p3));
            u32x2 w;
            w[0] = lo;
            w[1] = hi;
            pa[j] = __builtin_bit_cast(s16x4, w);
        }

        // ---- O += P V and rowsum += P*ones, via K=16 MFMAs per kv-block j
        __builtin_amdgcn_s_setprio(1);
#pragma unroll
        for (int j = 0; j < 4; j++) {
            MFMA16(osum, pa[j], ones16);
#pragma unroll
            for (int dj = 0; dj < 4; dj++) {
                int vrow = dj * 16 + c;
                u32x2 vv = *(const u32x2*)(bV + vrow * 128 +
                                           ((j * 32 + 8 * g) ^ ((vrow & 7) << 4)));
                s16x4 vfj = __builtin_bit_cast(s16x4, vv);
                MFMA16(o[dj], pa[j], vfj);
            }
        }
        __builtin_amdgcn_s_setprio(0);

        // ---- write next tile into the other buffer (read last in iter t-1)
        if (t < N_ / 64 - 1) {
            unsigned char* nK = smem + ((t + 1) & 1) * 8192;
            unsigned char* nV = smem + 16384 + ((t + 1) & 1) * 8192;
            *(u32x4*)(nK + srow * 128 + ssw) = kreg;
            *(u32x4*)(nV + srow * 128 + ssw) = vreg;
        }
        __syncthreads();
    }

    // ---- epilogue: AO[b][n][h*64+d] bf16  (osum[r] = rowsum(P) for q-row 4g+r)
    const int b = bh >> 3, h = bh & 7;
#pragma unroll
    for (int r = 0; r < 4; r++) {
        float inv = 1.0f / osum[r];
        int n = q0 + (g << 2) + r;
#pragma unroll
        for (int dj = 0; dj < 4; dj++) {
            int col = h * HD_ + dj * 16 + c;
            AO[((size_t)(b * N_ + n)) * C_ + col] = f2bf(o[dj][r] * inv);
        }
    }
}

// ---------------------------------------------------------------- launch
extern "C" void kernel_launch(void* const* d_in, const int* in_sizes, int n_in,
                              void* d_out, int out_size, void* d_ws, size_t ws_size,
                              hipStream_t stream) {
    const float* x = (const float*)d_in[0];
    const float* w_qkv = (const float*)d_in[1];
    const float* b_qkv = (const float*)d_in[2];
    const float* w_proj = (const float*)d_in[3];
    const float* b_proj = (const float*)d_in[4];
    float* out = (float*)d_out;

    // workspace layout: AO | wqb | wpb | Vt   (xb no longer needed — x is
    // converted in-flight inside gemm_qkv's A staging)
    unsigned char* ws = (unsigned char*)d_ws;
    unsigned short* AO = (unsigned short*)ws;                       // 8192*512 bf16 (8.39MB)
    unsigned short* wqb = (unsigned short*)(ws + 8388608);          // 1536*512 bf16
    unsigned short* wpb = (unsigned short*)(ws + 8388608 + 1572864);// 512*512 bf16
    unsigned short* Vt = (unsigned short*)(ws + 8388608 + 1572864 + 524288); // (B,H,64,N) bf16

    // d_out (16.78MB f32) doubles as scratch for Q,K bf16 (8.39MB each); proj GEMM
    // fully overwrites it at the end.
    unsigned short* Qb = (unsigned short*)d_out;
    unsigned short* Kb = Qb + (size_t)B_ * H_ * N_ * HD_;

    const int NW = (3 * C_ * C_ + C_ * C_) / 4;
    cvt_w<<<(NW + 255) / 256, 256, 0, stream>>>(w_qkv, w_proj, wqb, wpb);

    gemm_qkv<<<dim3(12, 64), 256, 0, stream>>>(x, wqb, b_qkv, Qb, Kb, Vt);
    attn_fwd<<<dim3(16, 32), 512, 0, stream>>>(Qb, Kb, Vt, AO);
    gemm_proj<<<dim3(4, 64), 256, 0, stream>>>(AO, wpb, b_proj, out);
}

// Round 23
// 115.983 us; speedup vs baseline: 1.0085x; 1.0085x over previous
//
#include <hip/hip_runtime.h>

#define B_ 4
#define N_ 2048
#define C_ 512
#define H_ 8
#define HD_ 64
#define SCALE_ 0.125f
// SCALE * log2(e): Q is pre-scaled by this so P = exp2(q.k) directly (v_exp_f32)
#define QSCALE_ 0.18033688011112042f

typedef __attribute__((ext_vector_type(8))) __bf16 bf16x8;
typedef __attribute__((ext_vector_type(4))) float f32x4;
typedef __attribute__((ext_vector_type(4))) unsigned int u32x4;
typedef __attribute__((ext_vector_type(2))) unsigned int u32x2;
typedef __attribute__((ext_vector_type(4))) short s16x4;

#if __has_builtin(__builtin_amdgcn_mfma_f32_16x16x16bf16_1k)
#define MFMA16(acc, a, b) acc = __builtin_amdgcn_mfma_f32_16x16x16bf16_1k(a, b, acc, 0, 0, 0)
#else
#define MFMA16(acc, a, b) \
    asm("v_mfma_f32_16x16x16_bf16 %0, %1, %2, %0" : "+v"(acc) : "v"(a), "v"(b))
#endif

__device__ __forceinline__ unsigned short f2bf(float f) {
    unsigned int u = __builtin_bit_cast(unsigned int, f);
    u += 0x7fffu + ((u >> 16) & 1u);
    return (unsigned short)(u >> 16);
}

__device__ __forceinline__ void llds16(const void* g, void* l) {
    __builtin_amdgcn_global_load_lds(
        (const __attribute__((address_space(1))) unsigned int*)g,
        (__attribute__((address_space(3))) unsigned int*)l, 16, 0, 0);
}

// stage one 16B bf16 LDS slot from an f32 row-major source:
// 2x f32x4 load -> 4x v_cvt_pk_bf16_f32 (RNE) -> linear ds_write_b128
__device__ __forceinline__ void stage_f32(const float* __restrict__ src, int ldk,
                                          int row, int col, unsigned char* dstslot) {
    const float* gp = src + (size_t)row * ldk + col;
    f32x4 a = *(const f32x4*)gp;
    f32x4 b = *(const f32x4*)(gp + 4);
    unsigned int w0, w1, w2, w3;
    asm("v_cvt_pk_bf16_f32 %0, %1, %2" : "=v"(w0) : "v"(a[0]), "v"(a[1]));
    asm("v_cvt_pk_bf16_f32 %0, %1, %2" : "=v"(w1) : "v"(a[2]), "v"(a[3]));
    asm("v_cvt_pk_bf16_f32 %0, %1, %2" : "=v"(w2) : "v"(b[0]), "v"(b[1]));
    asm("v_cvt_pk_bf16_f32 %0, %1, %2" : "=v"(w3) : "v"(b[2]), "v"(b[3]));
    u32x4 wv;
    wv[0] = w0; wv[1] = w1; wv[2] = w2; wv[3] = w3;
    *(u32x4*)dstslot = wv;
}

// ---------------------------------------------------------------- GEMM1: x(f32) @ w_qkv(f32)^T
// Both operands converted in-flight during staging (no cvt kernel). Epilogue:
// Q/K coalesced (B,H,N,64) writes (Q pre-scaled QSCALE_); V blocks transposed
// via LDS -> Vt (B,H,64,N) d-major coalesced.
__global__ __launch_bounds__(256) void gemm_qkv(const float* __restrict__ X,
                                                const float* __restrict__ Wq,
                                                const float* __restrict__ bias,
                                                unsigned short* __restrict__ Qb,
                                                unsigned short* __restrict__ Kb,
                                                unsigned short* __restrict__ Vt) {
    constexpr int K = 512;
    __shared__ __align__(16) unsigned char smem[32768];
    unsigned char* sA = smem;
    unsigned char* sB = smem + 16384;

    const int tid = threadIdx.x;
    const int lane = tid & 63;
    const int wave = tid >> 6;
    const int wm = wave >> 1, wn = wave & 1;
    const int m0 = blockIdx.y * 128;
    const int n0 = blockIdx.x * 128;

    f32x4 acc[4][4] = {};

    for (int k0 = 0; k0 < K; k0 += 64) {
#pragma unroll
        for (int i = 0; i < 4; i++) {
            int ci = wave * 4 + i;
            int row = ci * 8 + (lane >> 3);
            int col = k0 + (lane & 7) * 8;
            stage_f32(X, K, m0 + row, col, sA + ci * 1024 + lane * 16);
            stage_f32(Wq, K, n0 + row, col, sB + ci * 1024 + lane * 16);
        }
        __syncthreads();
#pragma unroll
        for (int kk = 0; kk < 2; kk++) {
            bf16x8 af[4], bfr[4];
#pragma unroll
            for (int mi = 0; mi < 4; mi++)
                af[mi] = *(const bf16x8*)(sA + (wm * 64 + mi * 16 + (lane & 15)) * 128 +
                                          kk * 64 + (lane >> 4) * 16);
#pragma unroll
            for (int ni = 0; ni < 4; ni++)
                bfr[ni] = *(const bf16x8*)(sB + (wn * 64 + ni * 16 + (lane & 15)) * 128 +
                                           kk * 64 + (lane >> 4) * 16);
#pragma unroll
            for (int mi = 0; mi < 4; mi++)
#pragma unroll
                for (int ni = 0; ni < 4; ni++)
                    acc[mi][ni] = __builtin_amdgcn_mfma_f32_16x16x32_bf16(
                        af[mi], bfr[ni], acc[mi][ni], 0, 0, 0);
        }
        __syncthreads();
    }

    if (n0 >= 1024) {
        // ---- V blocks: LDS transpose then coalesced d-major write
        unsigned char* T = smem;  // [128 c][128 m] bf16, byte = cl*256 + (ml*2 ^ ((cl&7)<<4))
#pragma unroll
        for (int ni = 0; ni < 4; ni++) {
            int cl = wn * 64 + ni * 16 + (lane & 15);
            float bv = bias[n0 + cl];
#pragma unroll
            for (int mi = 0; mi < 4; mi++) {
#pragma unroll
                for (int r = 0; r < 4; r++) {
                    int ml = wm * 64 + mi * 16 + ((lane >> 4) << 2) + r;
                    *(unsigned short*)(T + cl * 256 + ((ml * 2) ^ ((cl & 7) << 4))) =
                        f2bf(acc[mi][ni][r] + bv);
                }
            }
        }
        __syncthreads();
        const int b = m0 >> 11;
#pragma unroll
        for (int it = 0; it < 8; it++) {
            int li = it * 256 + tid;
            int cl2 = li >> 4, mc = li & 15;
            int cg = n0 + cl2;
            int h = (cg >> 6) & 7, d = cg & 63;
            u32x4 vv = *(const u32x4*)(T + cl2 * 256 + ((mc * 16) ^ ((cl2 & 7) << 4)));
            int n = (m0 & (N_ - 1)) + mc * 8;
            *(u32x4*)((unsigned char*)Vt +
                      (((size_t)(b * H_ + h) * HD_ + d) * N_ + n) * 2) = vv;
        }
    } else {
        // ---- Q/K blocks: direct coalesced (B,H,N,64) writes
        const bool selq = (n0 < 512);
#pragma unroll
        for (int ni = 0; ni < 4; ni++) {
            int cg = n0 + wn * 64 + ni * 16 + (lane & 15);
            int h = (cg >> 6) & 7, d = cg & 63;
            float bv = bias[cg];
#pragma unroll
            for (int mi = 0; mi < 4; mi++) {
#pragma unroll
                for (int r = 0; r < 4; r++) {
                    int m = m0 + wm * 64 + mi * 16 + ((lane >> 4) << 2) + r;
                    int b = m >> 11, n = m & (N_ - 1);
                    float fv = acc[mi][ni][r] + bv;
                    size_t idx = ((size_t)(b * H_ + h) * N_ + n) * HD_ + d;
                    if (selq) Qb[idx] = f2bf(fv * QSCALE_);
                    else Kb[idx] = f2bf(fv);
                }
            }
        }
    }
}

// ---------------------------------------------------------------- GEMM2: AO(bf16) @ w_proj(f32)^T
__global__ __launch_bounds__(256) void gemm_proj(const unsigned short* __restrict__ A,
                                                 const float* __restrict__ Wp,
                                                 const float* __restrict__ bias,
                                                 float* __restrict__ Out) {
    constexpr int K = 512;
    __shared__ __align__(16) unsigned char smem[32768];
    unsigned char* sA = smem;
    unsigned char* sB = smem + 16384;

    const int tid = threadIdx.x;
    const int lane = tid & 63;
    const int wave = tid >> 6;
    const int wm = wave >> 1, wn = wave & 1;
    const int m0 = blockIdx.y * 128;
    const int n0 = blockIdx.x * 128;

    f32x4 acc[4][4] = {};

    for (int k0 = 0; k0 < K; k0 += 64) {
#pragma unroll
        for (int i = 0; i < 4; i++) {
            int ci = wave * 4 + i;
            int row = ci * 8 + (lane >> 3);
            int cb = (lane & 7) * 16;
            const unsigned char* ga =
                (const unsigned char*)A + ((size_t)(m0 + row) * K + k0) * 2 + cb;
            llds16(ga, sA + ci * 1024);
            stage_f32(Wp, K, n0 + row, k0 + (lane & 7) * 8, sB + ci * 1024 + lane * 16);
        }
        __syncthreads();
#pragma unroll
        for (int kk = 0; kk < 2; kk++) {
            bf16x8 af[4], bfr[4];
#pragma unroll
            for (int mi = 0; mi < 4; mi++)
                af[mi] = *(const bf16x8*)(sA + (wm * 64 + mi * 16 + (lane & 15)) * 128 +
                                          kk * 64 + (lane >> 4) * 16);
#pragma unroll
            for (int ni = 0; ni < 4; ni++)
                bfr[ni] = *(const bf16x8*)(sB + (wn * 64 + ni * 16 + (lane & 15)) * 128 +
                                           kk * 64 + (lane >> 4) * 16);
#pragma unroll
            for (int mi = 0; mi < 4; mi++)
#pragma unroll
                for (int ni = 0; ni < 4; ni++)
                    acc[mi][ni] = __builtin_amdgcn_mfma_f32_16x16x32_bf16(
                        af[mi], bfr[ni], acc[mi][ni], 0, 0, 0);
        }
        __syncthreads();
    }

#pragma unroll
    for (int ni = 0; ni < 4; ni++) {
        int c = n0 + wn * 64 + ni * 16 + (lane & 15);
        float bv = bias[c];
#pragma unroll
        for (int mi = 0; mi < 4; mi++) {
#pragma unroll
            for (int r = 0; r < 4; r++) {
                int m = m0 + wm * 64 + mi * 16 + ((lane >> 4) << 2) + r;
                Out[(size_t)m * C_ + c] = acc[mi][ni][r] + bv;
            }
        }
    }
}

// ---------------------------------------------------------------- flash attention
// R18 structure (attn 65.5us, absmax 1.95e-3): 8 waves x 16 q-rows; KVBLK=64;
// swapped QK^T -> in-register P (K=16 PV); no-max exp2 softmax; ones-MFMA row
// sums; T5 setprio around MFMA clusters; unroll-2 tile loop; XCD block swizzle.
__global__ __launch_bounds__(512, 4) void attn_fwd(const unsigned short* __restrict__ Qb,
                                                   const unsigned short* __restrict__ Kb,
                                                   const unsigned short* __restrict__ Vt,
                                                   unsigned short* __restrict__ AO) {
    __shared__ __align__(16) unsigned char smem[32768];
    // sK buf0/1: 0, 8192 | sV buf0/1: 16384, 24576

    const int tid = threadIdx.x, lane = tid & 63, wave = tid >> 6;
    const int g = lane >> 4, c = lane & 15;
    // XCD-aware bijective swizzle: each XCD (L%8) owns 4 complete bh's.
    const int L = blockIdx.y * 16 + blockIdx.x;
    const int bh = (L & 7) * 4 + ((L >> 3) & 3);
    const int qx = L >> 5;
    const int q0 = qx * 128 + wave * 16;
    const unsigned short* Qh = Qb + (size_t)bh * N_ * HD_;
    const unsigned short* Kh = Kb + (size_t)bh * N_ * HD_;
    const unsigned short* Vh = Vt + (size_t)bh * HD_ * N_;

    // Q fragments (rows q0 + c), held for the whole kernel (B-operand of swapped QK)
    bf16x8 qf[2];
#pragma unroll
    for (int kk = 0; kk < 2; kk++)
        qf[kk] = *(const bf16x8*)(Qh + (size_t)(q0 + c) * HD_ + kk * 32 + g * 8);

    s16x4 ones16;
#pragma unroll
    for (int i = 0; i < 4; i++) ones16[i] = (short)0x3F80;  // bf16 1.0

    f32x4 o[4] = {};
    f32x4 osum = {};

    // staging geometry: one 16B chunk of K and of V per thread per tile
    const int srow = tid >> 3;
    const int sslot = (tid & 7) * 16;
    const int ssw = (sslot ^ ((srow & 7) << 4));

    // prologue: stage tile 0 into buf 0
    {
        u32x4 kreg = *(const u32x4*)((const unsigned char*)Kh + (size_t)srow * 128 + sslot);
        u32x4 vreg = *(const u32x4*)((const unsigned char*)Vh + (size_t)srow * (N_ * 2) + sslot);
        *(u32x4*)(smem + srow * 128 + ssw) = kreg;
        *(u32x4*)(smem + 16384 + srow * 128 + ssw) = vreg;
    }
    __syncthreads();

#pragma unroll 2
    for (int t = 0; t < N_ / 64; t++) {
        unsigned char* bK = smem + (t & 1) * 8192;
        unsigned char* bV = smem + 16384 + (t & 1) * 8192;

        // ---- issue next tile's global loads (latency hides under compute)
        u32x4 kreg, vreg;
        if (t < N_ / 64 - 1) {
            int kv0 = (t + 1) * 64;
            kreg = *(const u32x4*)((const unsigned char*)Kh + (size_t)(kv0 + srow) * 128 + sslot);
            vreg = *(const u32x4*)((const unsigned char*)Vh + (size_t)srow * (N_ * 2) +
                                   kv0 * 2 + sslot);
        }

        // ---- S^T = K Q^T (swapped operands): lane holds S[q=c][kv=j*16+4g+r]
        f32x4 s[4] = {};
        __builtin_amdgcn_s_setprio(1);
#pragma unroll
        for (int j = 0; j < 4; j++) {
#pragma unroll
            for (int kk = 0; kk < 2; kk++) {
                int krow = j * 16 + c;
                bf16x8 kf = *(const bf16x8*)(bK + krow * 128 +
                                             ((kk * 64 + g * 16) ^ ((krow & 7) << 4)));
                s[j] = __builtin_amdgcn_mfma_f32_16x16x32_bf16(kf, qf[kk], s[j], 0, 0, 0);
            }
        }
        __builtin_amdgcn_s_setprio(0);

        // ---- P = exp2(S^T); pack in-register into K=16 A-fragments (no LDS)
        s16x4 pa[4];
#pragma unroll
        for (int j = 0; j < 4; j++) {
            float p0 = __builtin_exp2f(s[j][0]);
            float p1 = __builtin_exp2f(s[j][1]);
            float p2 = __builtin_exp2f(s[j][2]);
            float p3 = __builtin_exp2f(s[j][3]);
            unsigned int lo, hi;
            asm("v_cvt_pk_bf16_f32 %0, %1, %2" : "=v"(lo) : "v"(p0), "v"(p1));
            asm("v_cvt_pk_bf16_f32 %0, %1, %2" : "=v"(hi) : "v"(p2), "v"(p3));
            u32x2 w;
            w[0] = lo;
            w[1] = hi;
            pa[j] = __builtin_bit_cast(s16x4, w);
        }

        // ---- O += P V and rowsum += P*ones, via K=16 MFMAs per kv-block j
        __builtin_amdgcn_s_setprio(1);
#pragma unroll
        for (int j = 0; j < 4; j++) {
            MFMA16(osum, pa[j], ones16);
#pragma unroll
            for (int dj = 0; dj < 4; dj++) {
                int vrow = dj * 16 + c;
                u32x2 vv = *(const u32x2*)(bV + vrow * 128 +
                                           ((j * 32 + 8 * g) ^ ((vrow & 7) << 4)));
                s16x4 vfj = __builtin_bit_cast(s16x4, vv);
                MFMA16(o[dj], pa[j], vfj);
            }
        }
        __builtin_amdgcn_s_setprio(0);

        // ---- write next tile into the other buffer (read last in iter t-1)
        if (t < N_ / 64 - 1) {
            unsigned char* nK = smem + ((t + 1) & 1) * 8192;
            unsigned char* nV = smem + 16384 + ((t + 1) & 1) * 8192;
            *(u32x4*)(nK + srow * 128 + ssw) = kreg;
            *(u32x4*)(nV + srow * 128 + ssw) = vreg;
        }
        __syncthreads();
    }

    // ---- epilogue: AO[b][n][h*64+d] bf16  (osum[r] = rowsum(P) for q-row 4g+r)
    const int b = bh >> 3, h = bh & 7;
#pragma unroll
    for (int r = 0; r < 4; r++) {
        float inv = 1.0f / osum[r];
        int n = q0 + (g << 2) + r;
#pragma unroll
        for (int dj = 0; dj < 4; dj++) {
            int col = h * HD_ + dj * 16 + c;
            AO[((size_t)(b * N_ + n)) * C_ + col] = f2bf(o[dj][r] * inv);
        }
    }
}

// ---------------------------------------------------------------- launch
extern "C" void kernel_launch(void* const* d_in, const int* in_sizes, int n_in,
                              void* d_out, int out_size, void* d_ws, size_t ws_size,
                              hipStream_t stream) {
    const float* x = (const float*)d_in[0];
    const float* w_qkv = (const float*)d_in[1];
    const float* b_qkv = (const float*)d_in[2];
    const float* w_proj = (const float*)d_in[3];
    const float* b_proj = (const float*)d_in[4];
    float* out = (float*)d_out;

    // workspace layout: AO | Vt  (weights converted in-flight; no cvt kernel)
    unsigned char* ws = (unsigned char*)d_ws;
    unsigned short* AO = (unsigned short*)ws;                       // 8192*512 bf16 (8.39MB)
    unsigned short* Vt = (unsigned short*)(ws + 8388608);           // (B,H,64,N) bf16 (4.19MB)

    // d_out (16.78MB f32) doubles as scratch for Q,K bf16 (8.39MB each); proj GEMM
    // fully overwrites it at the end.
    unsigned short* Qb = (unsigned short*)d_out;
    unsigned short* Kb = Qb + (size_t)B_ * H_ * N_ * HD_;

    gemm_qkv<<<dim3(12, 64), 256, 0, stream>>>(x, w_qkv, b_qkv, Qb, Kb, Vt);
    attn_fwd<<<dim3(16, 32), 512, 0, stream>>>(Qb, Kb, Vt, AO);
    gemm_proj<<<dim3(4, 64), 256, 0, stream>>>(AO, w_proj, b_proj, out);
}